// Round 7
// baseline (677.461 us; speedup 1.0000x reference)
//
#include <hip/hip_runtime.h>
#include <hip/hip_bf16.h>
#include <math.h>

#define TKN 16384
#define HID 4096
#define NE  256
#define TOPK 8
#define NGRP 8
#define TOPG 4

#define BM 128
#define BK 64
#define NKT (HID / BK)          // 64 K-steps
#define BIMG 32768              // prep'd B image per (cb,kt): [hi 16K][lo 16K]

typedef _Float16 half8 __attribute__((ext_vector_type(8)));
typedef float    f32x4 __attribute__((ext_vector_type(4)));
typedef unsigned uint4v __attribute__((ext_vector_type(4)));

static __device__ __forceinline__ unsigned pkrtz(float x, float y) {
    auto r = __builtin_amdgcn_cvt_pkrtz(x, y);   // v_cvt_pkrtz_f16_f32
    return __builtin_bit_cast(unsigned, r);
}
static __device__ __forceinline__ float hi_mask(float a) {
    return __uint_as_float(__float_as_uint(a) & 0xFFFFE000u);
}

// ---- prep: B [256][4096] f32 -> FRAGMENT-ORDERED f16 hi/lo images ----------
// (verbatim round 6 — validated) A wave's fragment load is base + lane*16.
__global__ __launch_bounds__(256) void prep_b(const float* __restrict__ B,
                                              unsigned char* __restrict__ ws)
{
    const int gid = blockIdx.x * 256 + threadIdx.x;   // 131072
    const int e   = gid >> 9;          // expert 0..255
    const int k0  = (gid & 511) * 8;   // k chunk of 8
    const float* src = B + (size_t)e * HID + k0;
    float v[8];
    #pragma unroll
    for (int i = 0; i < 8; ++i) v[i] = src[i];
    unsigned hw[4], lw[4];
    #pragma unroll
    for (int j = 0; j < 4; ++j) {
        const float x0 = v[2*j], x1 = v[2*j+1];
        const float h0 = hi_mask(x0), h1 = hi_mask(x1);
        hw[j] = pkrtz(h0, h1);
        lw[j] = pkrtz(x0 - h0, x1 - h1);
    }
    const int cb     = e >> 7;
    const int row    = e & 127;
    const int rowgrp = row >> 4;
    const int lane16 = row & 15;
    const int kt     = k0 >> 6;
    const int kk     = k0 & 63;
    const int wg     = kk >> 5;
    const int kseg   = (kk >> 3) & 3;
    const int idx16  = ((rowgrp * 2 + wg) * 4 + kseg) * 16 + lane16;
    unsigned char* img = ws + (size_t)(cb * NKT + kt) * BIMG + idx16 * 16;
    *(uint4*)(img)         = make_uint4(hw[0], hw[1], hw[2], hw[3]);
    *(uint4*)(img + 16384) = make_uint4(lw[0], lw[1], lw[2], lw[3]);
}

// ---- GEMM: logits = A[T,H] @ B[E,H]^T, f16x2 split, 3 MFMA passes ----------
// BARRIER-FREE K-loop: no LDS in the loop; each wave is independent.
// A fragments are loaded raw (float4 pairs, coalesced 16rows x 128B per
// instruction) one K-step ahead and converted in-loop with the IDENTICAL
// hi_mask/pkrtz pairing as the staged versions -> bit-identical MFMA inputs.
// Per-accumulator MFMA chain + split-K epilogue add are bit-identical to the
// passing rounds 3/5/6 kernels -> bit-identical logits.
__global__ __launch_bounds__(1024, 3) void gemm_mfma(
    const float* __restrict__ A, const unsigned char* __restrict__ Bws,
    float* __restrict__ C)
{
    __shared__ __align__(16) float redf[16384];   // 64 KB, epilogue only

    const int tid  = threadIdx.x;
    const int lane = tid & 63;
    const int wave = tid >> 6;
    const int wg = wave >> 3;           // split-K half
    const int wr = (wave >> 2) & 1;     // row 64-half
    const int wc = wave & 3;            // col 32-quarter

    const int bid  = blockIdx.x;
    const int mb   = (bid & 7) * 16 + (bid >> 4);
    const int cb   = (bid >> 3) & 1;
    const int row0 = mb * BM;

    // A fragment pointers: lane covers 8 consecutive floats of one row
    const int arow = row0 + wr * 64 + (lane & 15);
    const int akof = wg * 32 + (lane >> 4) * 8;
    const float* aF0 = A + (size_t)arow * HID + akof;
    const float* aF1 = aF0 + (size_t)16 * HID;
    const float* aF2 = aF0 + (size_t)32 * HID;
    const float* aF3 = aF0 + (size_t)48 * HID;

    // B fragment addressing: contiguous 1KB per wave-fragment (round-6 image)
    const unsigned char* bBase = Bws + (size_t)cb * NKT * BIMG;
    const int boffH0 = ((wc * 2 + 0) * 2 + wg) * 1024 + lane * 16;
    const int boffH1 = ((wc * 2 + 1) * 2 + wg) * 1024 + lane * 16;

    f32x4 acc[4][2];
    #pragma unroll
    for (int i = 0; i < 4; ++i) { acc[i][0] = (f32x4)0.f; acc[i][1] = (f32x4)0.f; }

    float4 rC[8], rN[8];
    half8  bC[4], bN[4];

    // prologue: kt=0 raw A + B frags
    rC[0] = *(const float4*)(aF0);     rC[1] = *(const float4*)(aF0 + 4);
    rC[2] = *(const float4*)(aF1);     rC[3] = *(const float4*)(aF1 + 4);
    rC[4] = *(const float4*)(aF2);     rC[5] = *(const float4*)(aF2 + 4);
    rC[6] = *(const float4*)(aF3);     rC[7] = *(const float4*)(aF3 + 4);
    bC[0] = *(const half8*)(bBase + boffH0);
    bC[1] = *(const half8*)(bBase + 16384 + boffH0);
    bC[2] = *(const half8*)(bBase + boffH1);
    bC[3] = *(const half8*)(bBase + 16384 + boffH1);

#define GSTEP(KT, BCUR, BNXT, RCUR, RNXT)                                      \
    {                                                                          \
        const int kt_ = (KT);                                                  \
        if (kt_ != NKT - 1) {   /* issue kt+1 loads: A (HBM) + B (L2) */       \
            const int ko = (kt_ + 1) * BK;                                     \
            RNXT[0] = *(const float4*)(aF0 + ko);                              \
            RNXT[1] = *(const float4*)(aF0 + ko + 4);                          \
            RNXT[2] = *(const float4*)(aF1 + ko);                              \
            RNXT[3] = *(const float4*)(aF1 + ko + 4);                          \
            RNXT[4] = *(const float4*)(aF2 + ko);                              \
            RNXT[5] = *(const float4*)(aF2 + ko + 4);                          \
            RNXT[6] = *(const float4*)(aF3 + ko);                              \
            RNXT[7] = *(const float4*)(aF3 + ko + 4);                          \
            const unsigned char* bp = bBase + (size_t)(kt_ + 1) * BIMG;        \
            BNXT[0] = *(const half8*)(bp + boffH0);                            \
            BNXT[1] = *(const half8*)(bp + 16384 + boffH0);                    \
            BNXT[2] = *(const half8*)(bp + boffH1);                            \
            BNXT[3] = *(const half8*)(bp + 16384 + boffH1);                    \
        }                                                                      \
        __builtin_amdgcn_sched_barrier(0);                                     \
        _Pragma("unroll")                                                      \
        for (int mt = 0; mt < 4; ++mt) {                                       \
            const float4 u0 = RCUR[2 * mt], u1 = RCUR[2 * mt + 1];             \
            const float h0 = hi_mask(u0.x), h1 = hi_mask(u0.y),                \
                        h2 = hi_mask(u0.z), h3 = hi_mask(u0.w);                \
            const float h4 = hi_mask(u1.x), h5 = hi_mask(u1.y),                \
                        h6 = hi_mask(u1.z), h7 = hi_mask(u1.w);                \
            uint4v ahv, alv;                                                   \
            ahv[0] = pkrtz(h0, h1);          ahv[1] = pkrtz(h2, h3);           \
            ahv[2] = pkrtz(h4, h5);          ahv[3] = pkrtz(h6, h7);           \
            alv[0] = pkrtz(u0.x - h0, u0.y - h1);                              \
            alv[1] = pkrtz(u0.z - h2, u0.w - h3);                              \
            alv[2] = pkrtz(u1.x - h4, u1.y - h5);                              \
            alv[3] = pkrtz(u1.z - h6, u1.w - h7);                              \
            const half8 ah = __builtin_bit_cast(half8, ahv);                   \
            const half8 al = __builtin_bit_cast(half8, alv);                   \
            f32x4 c0 = acc[mt][0];                                             \
            c0 = __builtin_amdgcn_mfma_f32_16x16x32_f16(ah, BCUR[0], c0, 0, 0, 0); \
            c0 = __builtin_amdgcn_mfma_f32_16x16x32_f16(ah, BCUR[1], c0, 0, 0, 0); \
            c0 = __builtin_amdgcn_mfma_f32_16x16x32_f16(al, BCUR[0], c0, 0, 0, 0); \
            acc[mt][0] = c0;                                                   \
            f32x4 c1 = acc[mt][1];                                             \
            c1 = __builtin_amdgcn_mfma_f32_16x16x32_f16(ah, BCUR[2], c1, 0, 0, 0); \
            c1 = __builtin_amdgcn_mfma_f32_16x16x32_f16(ah, BCUR[3], c1, 0, 0, 0); \
            c1 = __builtin_amdgcn_mfma_f32_16x16x32_f16(al, BCUR[2], c1, 0, 0, 0); \
            acc[mt][1] = c1;                                                   \
        }                                                                      \
    }

    for (int kt = 0; kt < NKT; kt += 2) {
        GSTEP(kt,     bC, bN, rC, rN);
        GSTEP(kt + 1, bN, bC, rN, rC);
    }
#undef GSTEP

    // epilogue: reduce wg1 into wg0 through LDS (rounds-3/5/6 verbatim), write C
    const int fb = (wave & 7) * 2048 + lane * 4;     // float index
    if (wg == 1) {
        #pragma unroll
        for (int mt = 0; mt < 4; ++mt)
            #pragma unroll
            for (int nt = 0; nt < 2; ++nt)
                *(f32x4*)&redf[fb + (mt * 2 + nt) * 256] = acc[mt][nt];
    }
    __syncthreads();
    if (wg == 0) {
        #pragma unroll
        for (int mt = 0; mt < 4; ++mt) {
            #pragma unroll
            for (int nt = 0; nt < 2; ++nt) {
                f32x4 o = acc[mt][nt] + *(const f32x4*)&redf[fb + (mt * 2 + nt) * 256];
                const int r0 = row0 + wr * 64 + mt * 16 + (lane >> 4) * 4;
                const int cc = cb * 128 + wc * 32 + nt * 16 + (lane & 15);
                #pragma unroll
                for (int r = 0; r < 4; ++r)
                    C[(size_t)(r0 + r) * NE + cc] = o[r];
            }
        }
    }
}

// ---------------- Router: per-token top-k (verified rounds 1-3, 5, 6) -------
__global__ __launch_bounds__(256) void router_topk_kernel(
    const float* __restrict__ logits, const float* __restrict__ bias,
    float* __restrict__ out_w, float* __restrict__ out_i)
{
    const int wid  = threadIdx.x >> 6;
    const int lane = threadIdx.x & 63;
    const int token = blockIdx.x * 4 + wid;

    const float* row = logits + (size_t)token * NE;
    const float4 lg = *(const float4*)&row[lane * 4];

    float sig[4], sc[4];
    {
        const float l4[4] = {lg.x, lg.y, lg.z, lg.w};
        #pragma unroll
        for (int j = 0; j < 4; ++j) {
            sig[j] = 1.f / (1.f + expf(-l4[j]));
            sc[j]  = sig[j] + bias[lane * 4 + j];
        }
    }

    float m1 = sc[0], m2 = -INFINITY;
    #pragma unroll
    for (int j = 1; j < 4; ++j) {
        if (sc[j] > m1) { m2 = m1; m1 = sc[j]; }
        else if (sc[j] > m2) { m2 = sc[j]; }
    }
    #pragma unroll
    for (int off = 1; off < 8; off <<= 1) {
        const float o1 = __shfl_xor(m1, off);
        const float o2 = __shfl_xor(m2, off);
        const float lo = fminf(m1, o1);
        m1 = fmaxf(m1, o1);
        m2 = fmaxf(lo, fmaxf(m2, o2));
    }
    const float gscore = m1 + m2;

    const int gmy = lane >> 3;
    int rank = 0;
    #pragma unroll
    for (int g = 0; g < NGRP; ++g) {
        const float gs = __shfl(gscore, g * 8);
        if (gs > gscore || (gs == gscore && g < gmy)) ++rank;
    }
    if (rank >= TOPG) {
        #pragma unroll
        for (int j = 0; j < 4; ++j) sc[j] = -INFINITY;
    }

    float wk[TOPK]; int ik[TOPK];
    float wsum = 0.f;
    #pragma unroll
    for (int k = 0; k < TOPK; ++k) {
        float bv = sc[0]; int bi = lane * 4;
        #pragma unroll
        for (int j = 1; j < 4; ++j)
            if (sc[j] > bv) { bv = sc[j]; bi = lane * 4 + j; }
        #pragma unroll
        for (int off = 1; off < 64; off <<= 1) {
            const float v2 = __shfl_xor(bv, off);
            const int   i2 = __shfl_xor(bi, off);
            if (v2 > bv || (v2 == bv && i2 < bi)) { bv = v2; bi = i2; }
        }
        const int owner = bi >> 2;
        const int j = bi & 3;
        const float sv = (j == 0) ? sig[0] : (j == 1) ? sig[1] : (j == 2) ? sig[2] : sig[3];
        const float w = __shfl(sv, owner);
        wk[k] = w; ik[k] = bi; wsum += w;
        if (lane == owner) {
            if (j == 0) sc[0] = -INFINITY;
            else if (j == 1) sc[1] = -INFINITY;
            else if (j == 2) sc[2] = -INFINITY;
            else sc[3] = -INFINITY;
        }
    }

    if (lane == 0) {
        const float denom = wsum + 1e-20f;
        #pragma unroll
        for (int k = 0; k < TOPK; ++k) {
            out_w[(size_t)token * TOPK + k] = wk[k] / denom;
            out_i[(size_t)token * TOPK + k] = (float)ik[k];
        }
    }
}

extern "C" void kernel_launch(void* const* d_in, const int* in_sizes, int n_in,
                              void* d_out, int out_size, void* d_ws, size_t ws_size,
                              hipStream_t stream) {
    const float* hidden = (const float*)d_in[0];
    const float* weight = (const float*)d_in[1];
    const float* bias   = (const float*)d_in[2];

    float* logits = (float*)d_out;                              // [T, E]
    float* out_w  = logits + (size_t)TKN * NE;                  // [T, 8]
    float* out_i  = out_w + (size_t)TKN * TOPK;                 // [T, 8]

    unsigned char* bpl = (unsigned char*)d_ws;                  // 4 MB B planes

    prep_b<<<512, 256, 0, stream>>>(weight, bpl);
    gemm_mfma<<<256, 1024, 0, stream>>>(hidden, bpl, logits);
    router_topk_kernel<<<TKN / 4, 256, 0, stream>>>(logits, bias, out_w, out_i);
}

// Round 8
// 171.793 us; speedup vs baseline: 3.9435x; 3.9435x over previous
//
#include <hip/hip_runtime.h>
#include <hip/hip_bf16.h>
#include <math.h>

#define TKN 16384
#define HID 4096
#define NE  256
#define TOPK 8
#define NGRP 8
#define TOPG 4

#define BM 128
#define BN 64
#define BK 64
#define NKT (HID / BK)          // 64 K-steps
#define BIMG 16384              // prep'd B image per (cb,kt): 8 frags x [hi 1K][lo 1K]

typedef _Float16 half8 __attribute__((ext_vector_type(8)));
typedef float    f32x4 __attribute__((ext_vector_type(4)));

static __device__ __forceinline__ unsigned pkrtz(float x, float y) {
    auto r = __builtin_amdgcn_cvt_pkrtz(x, y);   // v_cvt_pkrtz_f16_f32
    return __builtin_bit_cast(unsigned, r);
}
static __device__ __forceinline__ float hi_mask(float a) {
    return __uint_as_float(__float_as_uint(a) & 0xFFFFE000u);
}

// ---- prep: B [256][4096] f32 -> FRAGMENT-ORDERED f16 hi/lo images ----------
// Image per (cb 0..3, kt): fragment f = colgrp*2 + wg (colgrp = (col&63)>>4),
// 2 KB each: [hi 1KB][lo 1KB]; within: (kseg*16 + col&15)*16 bytes = lane*16.
// f16 hi/lo values identical to all passing rounds (bit-identical MFMA inputs).
__global__ __launch_bounds__(256) void prep_b(const float* __restrict__ B,
                                              unsigned char* __restrict__ ws)
{
    const int gid = blockIdx.x * 256 + threadIdx.x;   // 131072
    const int e   = gid >> 9;          // expert 0..255
    const int k0  = (gid & 511) * 8;   // k chunk of 8
    const float* src = B + (size_t)e * HID + k0;
    float v[8];
    #pragma unroll
    for (int i = 0; i < 8; ++i) v[i] = src[i];
    unsigned hw[4], lw[4];
    #pragma unroll
    for (int j = 0; j < 4; ++j) {
        const float x0 = v[2*j], x1 = v[2*j+1];
        const float h0 = hi_mask(x0), h1 = hi_mask(x1);
        hw[j] = pkrtz(h0, h1);
        lw[j] = pkrtz(x0 - h0, x1 - h1);
    }
    const int cb     = e >> 6;
    const int colgrp = (e & 63) >> 4;
    const int lane16 = e & 15;
    const int kt     = k0 >> 6;
    const int kk     = k0 & 63;
    const int wg     = kk >> 5;
    const int kseg   = (kk >> 3) & 3;
    const int f      = colgrp * 2 + wg;
    unsigned char* img = ws + (size_t)(cb * NKT + kt) * BIMG
                            + f * 2048 + (kseg * 16 + lane16) * 16;
    *(uint4*)(img)        = make_uint4(hw[0], hw[1], hw[2], hw[3]);
    *(uint4*)(img + 1024) = make_uint4(lw[0], lw[1], lw[2], lw[3]);
}

// ---- GEMM: logits = A[T,H] @ B[E,H]^T, f16x2 split, 3 MFMA passes ----------
// 128x64 tile, 8 waves (wg2 x wr2 x wc2), grid 512 = 2 blocks/CU so barrier
// drains of one block overlap compute of the other. Per-accumulator MFMA
// chain + split-K epilogue add bit-identical to passing rounds 3/5/6.
__global__ __launch_bounds__(512, 4) void gemm_mfma(
    const float* __restrict__ A, const unsigned char* __restrict__ Bws,
    float* __restrict__ C)
{
    __shared__ __align__(16) unsigned char smem[2][2][16384];   // 64 KiB

    const int tid  = threadIdx.x;
    const int lane = tid & 63;
    const int wave = tid >> 6;
    const int wg = wave >> 2;           // split-K half
    const int wr = (wave >> 1) & 1;     // row 64-half
    const int wc = wave & 1;            // col 32-half

    // XCD-bijective remap: each XCD owns 64 contiguous logical tiles;
    // cb-quads (same A panel) co-resident on one XCD -> A fetched ~once.
    const int logical = (blockIdx.x & 7) * 64 + (blockIdx.x >> 3);
    const int mb   = logical >> 2;
    const int cb   = logical & 3;
    const int row0 = mb * BM;

    // A staging: thread owns 16 consecutive k-floats of one row
    const int arow = tid >> 2;                   // 0..127
    const int aseg = (tid & 3) * 16;             // float idx 0,16,32,48
    const float* aG = A + (size_t)(row0 + arow) * HID + aseg;
    const int xorw = (arow & 7) << 4;
    const int awx0 = arow * 128 + ((aseg * 2) ^ xorw);
    const int awx1 = arow * 128 + ((aseg * 2 + 16) ^ xorw);

    // A fragment addressing (identical math to rounds 3/5/6; 0 conflicts)
    const int kx    = ((wg * 64) + ((lane >> 4) << 4)) ^ ((lane & 7) << 4);
    const int aRowB = (wr * 64 + (lane & 15)) * 128;

    // B fragment offsets within a (cb,kt) image
    const unsigned char* bBase = Bws + (size_t)cb * NKT * BIMG;
    const int f0off = ((wc * 2 + 0) * 2 + wg) * 2048 + lane * 16;
    const int f1off = ((wc * 2 + 1) * 2 + wg) * 2048 + lane * 16;

    f32x4 acc[4][2];
    #pragma unroll
    for (int i = 0; i < 4; ++i) { acc[i][0] = (f32x4)0.f; acc[i][1] = (f32x4)0.f; }

    float4 av[4];
    half8 bC[4], bN[4];   // [bh0, bl0, bh1, bl1] current / next

    // prologue: A tile 0 staged to buf 0; B frags kt=0 in regs
    #pragma unroll
    for (int i = 0; i < 4; ++i) av[i] = *(const float4*)(aG + i * 4);
    bC[0] = *(const half8*)(bBase + f0off);
    bC[1] = *(const half8*)(bBase + f0off + 1024);
    bC[2] = *(const half8*)(bBase + f1off);
    bC[3] = *(const half8*)(bBase + f1off + 1024);
    {
        unsigned hw[8], lw[8];
        const float f[16] = {av[0].x,av[0].y,av[0].z,av[0].w, av[1].x,av[1].y,av[1].z,av[1].w,
                             av[2].x,av[2].y,av[2].z,av[2].w, av[3].x,av[3].y,av[3].z,av[3].w};
        #pragma unroll
        for (int j = 0; j < 8; ++j) {
            const float h0 = hi_mask(f[2*j]), h1 = hi_mask(f[2*j+1]);
            hw[j] = pkrtz(h0, h1);
            lw[j] = pkrtz(f[2*j] - h0, f[2*j+1] - h1);
        }
        *(uint4*)&smem[0][0][awx0] = make_uint4(hw[0], hw[1], hw[2], hw[3]);
        *(uint4*)&smem[0][0][awx1] = make_uint4(hw[4], hw[5], hw[6], hw[7]);
        *(uint4*)&smem[0][1][awx0] = make_uint4(lw[0], lw[1], lw[2], lw[3]);
        *(uint4*)&smem[0][1][awx1] = make_uint4(lw[4], lw[5], lw[6], lw[7]);
    }
    __syncthreads();

#define GSTEP(KT, BCUR, BNXT)                                                  \
    {                                                                          \
        const int kt_ = (KT);                                                  \
        const unsigned char* ub = &smem[kt_ & 1][0][0];                        \
        const bool more = (kt_ != NKT - 1);                                    \
        if (more) {  /* issue kt+1 loads: A (HBM) + B (L2) */                  \
            const float* ap = aG + (kt_ + 1) * BK;                             \
            av[0] = *(const float4*)(ap);                                      \
            av[1] = *(const float4*)(ap + 4);                                  \
            av[2] = *(const float4*)(ap + 8);                                  \
            av[3] = *(const float4*)(ap + 12);                                 \
            const unsigned char* bp = bBase + (size_t)(kt_ + 1) * BIMG;        \
            BNXT[0] = *(const half8*)(bp + f0off);                             \
            BNXT[1] = *(const half8*)(bp + f0off + 1024);                      \
            BNXT[2] = *(const half8*)(bp + f1off);                             \
            BNXT[3] = *(const half8*)(bp + f1off + 1024);                      \
        }                                                                      \
        __builtin_amdgcn_sched_barrier(0);                                     \
        _Pragma("unroll")                                                      \
        for (int mt = 0; mt < 4; ++mt) {                                       \
            const half8 ah = *(const half8*)(ub + aRowB + mt * 2048 + kx);     \
            const half8 al = *(const half8*)(ub + 16384 + aRowB + mt * 2048 + kx); \
            f32x4 c0 = acc[mt][0];                                             \
            c0 = __builtin_amdgcn_mfma_f32_16x16x32_f16(ah, BCUR[0], c0, 0, 0, 0); \
            c0 = __builtin_amdgcn_mfma_f32_16x16x32_f16(ah, BCUR[1], c0, 0, 0, 0); \
            c0 = __builtin_amdgcn_mfma_f32_16x16x32_f16(al, BCUR[0], c0, 0, 0, 0); \
            acc[mt][0] = c0;                                                   \
            f32x4 c1 = acc[mt][1];                                             \
            c1 = __builtin_amdgcn_mfma_f32_16x16x32_f16(ah, BCUR[2], c1, 0, 0, 0); \
            c1 = __builtin_amdgcn_mfma_f32_16x16x32_f16(ah, BCUR[3], c1, 0, 0, 0); \
            c1 = __builtin_amdgcn_mfma_f32_16x16x32_f16(al, BCUR[2], c1, 0, 0, 0); \
            acc[mt][1] = c1;                                                   \
        }                                                                      \
        if (more) {  /* stage kt+1 A (loads had the full MFMA section) */      \
            const int nb = (kt_ + 1) & 1;                                      \
            unsigned hw[8], lw[8];                                             \
            const float f[16] = {av[0].x,av[0].y,av[0].z,av[0].w,              \
                                 av[1].x,av[1].y,av[1].z,av[1].w,              \
                                 av[2].x,av[2].y,av[2].z,av[2].w,              \
                                 av[3].x,av[3].y,av[3].z,av[3].w};             \
            _Pragma("unroll")                                                  \
            for (int j = 0; j < 8; ++j) {                                      \
                const float h0 = hi_mask(f[2*j]), h1 = hi_mask(f[2*j+1]);      \
                hw[j] = pkrtz(h0, h1);                                         \
                lw[j] = pkrtz(f[2*j] - h0, f[2*j+1] - h1);                     \
            }                                                                  \
            *(uint4*)&smem[nb][0][awx0] = make_uint4(hw[0], hw[1], hw[2], hw[3]); \
            *(uint4*)&smem[nb][0][awx1] = make_uint4(hw[4], hw[5], hw[6], hw[7]); \
            *(uint4*)&smem[nb][1][awx0] = make_uint4(lw[0], lw[1], lw[2], lw[3]); \
            *(uint4*)&smem[nb][1][awx1] = make_uint4(lw[4], lw[5], lw[6], lw[7]); \
        }                                                                      \
        __syncthreads();                                                       \
    }

    for (int kt = 0; kt < NKT; kt += 2) {
        GSTEP(kt,     bC, bN);
        GSTEP(kt + 1, bN, bC);
    }
#undef GSTEP

    // epilogue: reduce wg1 into wg0 through LDS (same math as rounds 3/5/6)
    float* redf = (float*)&smem[0][0][0];            // scratch (loop done)
    const int fb = (wave & 3) * 2048 + lane * 4;     // float index
    if (wg == 1) {
        #pragma unroll
        for (int mt = 0; mt < 4; ++mt)
            #pragma unroll
            for (int nt = 0; nt < 2; ++nt)
                *(f32x4*)&redf[fb + (mt * 2 + nt) * 256] = acc[mt][nt];
    }
    __syncthreads();
    if (wg == 0) {
        #pragma unroll
        for (int mt = 0; mt < 4; ++mt) {
            #pragma unroll
            for (int nt = 0; nt < 2; ++nt) {
                f32x4 o = acc[mt][nt] + *(const f32x4*)&redf[fb + (mt * 2 + nt) * 256];
                const int r0 = row0 + wr * 64 + mt * 16 + (lane >> 4) * 4;
                const int cc = cb * BN + wc * 32 + nt * 16 + (lane & 15);
                #pragma unroll
                for (int r = 0; r < 4; ++r)
                    C[(size_t)(r0 + r) * NE + cc] = o[r];
            }
        }
    }
}

// ---------------- Router: per-token top-k (verified rounds 1-3, 5, 6) -------
__global__ __launch_bounds__(256) void router_topk_kernel(
    const float* __restrict__ logits, const float* __restrict__ bias,
    float* __restrict__ out_w, float* __restrict__ out_i)
{
    const int wid  = threadIdx.x >> 6;
    const int lane = threadIdx.x & 63;
    const int token = blockIdx.x * 4 + wid;

    const float* row = logits + (size_t)token * NE;
    const float4 lg = *(const float4*)&row[lane * 4];

    float sig[4], sc[4];
    {
        const float l4[4] = {lg.x, lg.y, lg.z, lg.w};
        #pragma unroll
        for (int j = 0; j < 4; ++j) {
            sig[j] = 1.f / (1.f + expf(-l4[j]));
            sc[j]  = sig[j] + bias[lane * 4 + j];
        }
    }

    float m1 = sc[0], m2 = -INFINITY;
    #pragma unroll
    for (int j = 1; j < 4; ++j) {
        if (sc[j] > m1) { m2 = m1; m1 = sc[j]; }
        else if (sc[j] > m2) { m2 = sc[j]; }
    }
    #pragma unroll
    for (int off = 1; off < 8; off <<= 1) {
        const float o1 = __shfl_xor(m1, off);
        const float o2 = __shfl_xor(m2, off);
        const float lo = fminf(m1, o1);
        m1 = fmaxf(m1, o1);
        m2 = fmaxf(lo, fmaxf(m2, o2));
    }
    const float gscore = m1 + m2;

    const int gmy = lane >> 3;
    int rank = 0;
    #pragma unroll
    for (int g = 0; g < NGRP; ++g) {
        const float gs = __shfl(gscore, g * 8);
        if (gs > gscore || (gs == gscore && g < gmy)) ++rank;
    }
    if (rank >= TOPG) {
        #pragma unroll
        for (int j = 0; j < 4; ++j) sc[j] = -INFINITY;
    }

    float wk[TOPK]; int ik[TOPK];
    float wsum = 0.f;
    #pragma unroll
    for (int k = 0; k < TOPK; ++k) {
        float bv = sc[0]; int bi = lane * 4;
        #pragma unroll
        for (int j = 1; j < 4; ++j)
            if (sc[j] > bv) { bv = sc[j]; bi = lane * 4 + j; }
        #pragma unroll
        for (int off = 1; off < 64; off <<= 1) {
            const float v2 = __shfl_xor(bv, off);
            const int   i2 = __shfl_xor(bi, off);
            if (v2 > bv || (v2 == bv && i2 < bi)) { bv = v2; bi = i2; }
        }
        const int owner = bi >> 2;
        const int j = bi & 3;
        const float sv = (j == 0) ? sig[0] : (j == 1) ? sig[1] : (j == 2) ? sig[2] : sig[3];
        const float w = __shfl(sv, owner);
        wk[k] = w; ik[k] = bi; wsum += w;
        if (lane == owner) {
            if (j == 0) sc[0] = -INFINITY;
            else if (j == 1) sc[1] = -INFINITY;
            else if (j == 2) sc[2] = -INFINITY;
            else sc[3] = -INFINITY;
        }
    }

    if (lane == 0) {
        const float denom = wsum + 1e-20f;
        #pragma unroll
        for (int k = 0; k < TOPK; ++k) {
            out_w[(size_t)token * TOPK + k] = wk[k] / denom;
            out_i[(size_t)token * TOPK + k] = (float)ik[k];
        }
    }
}

extern "C" void kernel_launch(void* const* d_in, const int* in_sizes, int n_in,
                              void* d_out, int out_size, void* d_ws, size_t ws_size,
                              hipStream_t stream) {
    const float* hidden = (const float*)d_in[0];
    const float* weight = (const float*)d_in[1];
    const float* bias   = (const float*)d_in[2];

    float* logits = (float*)d_out;                              // [T, E]
    float* out_w  = logits + (size_t)TKN * NE;                  // [T, 8]
    float* out_i  = out_w + (size_t)TKN * TOPK;                 // [T, 8]

    unsigned char* bpl = (unsigned char*)d_ws;                  // 4 MB B images

    prep_b<<<512, 256, 0, stream>>>(weight, bpl);
    gemm_mfma<<<512, 512, 0, stream>>>(hidden, bpl, logits);
    router_topk_kernel<<<TKN / 4, 256, 0, stream>>>(logits, bias, out_w, out_i);
}